// Round 4
// baseline (552.555 us; speedup 1.0000x reference)
//
#include <hip/hip_runtime.h>
#include <math.h>

#define B 8192
#define D 512
#define NH 4
#define M 128
#define W 64
#define HW 256   // NH * W
#define TILE 16  // batch rows per block
#define EPS 1e-6f

// Swizzle in float4 units within a 128x64f batch tile: row m = j>>4 (16
// float4/row), col c = j&15; physical col = c ^ (m&15). Spreads the
// stride-256B row reads of phase C across all LDS banks (T2 pattern).
__device__ __forceinline__ int swz(int j) {
    return (j & ~15) | ((j & 15) ^ ((j >> 4) & 15));
}

// ---------------------------------------------------------------------------
// Fully fused kernel: one block = 16 batches, 512 threads, 3 phases.
//
// Phase A: stage hidden tile (16 x 512, 32 KB) into LDS, coalesced float4.
// Phase B: key = tanh(hidden @ W_key + b); 8-row x 1-col per thread
//          (VALU-bound at the fp32 floor; no fp32 MFMA on CDNA4).
//          u2 via full-wave butterfly; beta tail from L2-warm global.
// Phase C: REWRITTEN. Old design read mem rows with 256-B lane stride ->
//          64 cache lines per load instruction -> MSHR-serialized, 15% HBM.
//          Now: batches processed sequentially by the whole block.
//          - next batch loaded COALESCED (1 KB/instr) into registers early
//            (T14 split: issue before compute, ds_write after barrier);
//            batch 0 issued at kernel top so it lands under phase B.
//          - XOR-swizzled LDS tile -> stride-64f row reads conflict-free.
//          - thread = (row m=t>>2, quarter q=t&3): 80 FMA from LDS, 2-step
//            shfl q-reduce, lane keeps head q only (1 exp/sqrt/div).
//          - NO max-subtraction: |logit| <= beta = softplus(~N(0,1/3)) <~ 3,
//            exp can't overflow; softmax ratio mathematically unchanged.
//          - cross-wave softmax sum via tiny red[8][4] LDS combine.
//          3 barriers/batch; HBM-paced at the 268 MB compulsory stream.
// ---------------------------------------------------------------------------
__global__ __launch_bounds__(512, 4) void fused_dynhead(const float* __restrict__ hid,
                                                        const float* __restrict__ mem,
                                                        const float* __restrict__ Wk,
                                                        const float* __restrict__ bk,
                                                        const float* __restrict__ Wb,
                                                        const float* __restrict__ bb,
                                                        float* __restrict__ out) {
    const int t  = threadIdx.x;
    const int i0 = blockIdx.x * TILE;

    __shared__ float hl[TILE * D];      // 32 KB: hidden tile, then mem-batch tile
    __shared__ float kl[TILE][HW];      // 16 KB key tile
    __shared__ float u2s[TILE][NH];
    __shared__ float bts[TILE][NH];
    __shared__ float red[8][NH];

    // ---- Phase C batch-0 preload: in flight during phases A and B ---------
    float4 cur[4];
    {
        const float4* src0 = (const float4*)(mem + (size_t)i0 * (M * W));
#pragma unroll
        for (int c = 0; c < 4; ++c) cur[c] = src0[t + c * 512];
    }

    // ---- Phase A: stage hidden --------------------------------------------
    {
        const float4* src = (const float4*)(hid + (size_t)i0 * D);
        float4* dst = (float4*)hl;
#pragma unroll
        for (int c = 0; c < 4; ++c)
            dst[t + c * 512] = src[t + c * 512];
    }
    __syncthreads();

    // ---- Phase B: key GEMM + tanh + u2 + beta -----------------------------
    {
        const int tx = t & 255;       // output column 0..255
        const int ty = t >> 8;        // 0..1 -> rows 8*ty .. 8*ty+7
        const float* hrows = hl + (8 * ty) * D;
        const float* wcol  = Wk + tx;

        float acc[8];
#pragma unroll
        for (int r = 0; r < 8; ++r) acc[r] = 0.f;

#pragma unroll 2
        for (int d = 0; d < D; d += 4) {
            const float w0 = wcol[(size_t)(d + 0) * HW];
            const float w1 = wcol[(size_t)(d + 1) * HW];
            const float w2 = wcol[(size_t)(d + 2) * HW];
            const float w3 = wcol[(size_t)(d + 3) * HW];
#pragma unroll
            for (int r = 0; r < 8; ++r) {
                const float4 x = *(const float4*)&hrows[r * D + d];
                acc[r] = fmaf(x.w, w3, fmaf(x.z, w2, fmaf(x.y, w1, fmaf(x.x, w0, acc[r]))));
            }
        }

        const float bj = bk[tx];
        float k[8];
#pragma unroll
        for (int r = 0; r < 8; ++r) {
            k[r] = tanhf(acc[r] + bj);
            kl[8 * ty + r][tx] = k[r];
        }

        // u2 per (row, head): wave spans exactly one head's 64 columns
        float s[8];
#pragma unroll
        for (int r = 0; r < 8; ++r) s[r] = k[r] * k[r];
#pragma unroll
        for (int off = 1; off < 64; off <<= 1) {
#pragma unroll
            for (int r = 0; r < 8; ++r) s[r] += __shfl_xor(s[r], off, 64);
        }
        if ((t & 63) == 0) {
            const int h = (t >> 6) & 3;
#pragma unroll
            for (int r = 0; r < 8; ++r)
                u2s[8 * ty + r][h] = s[r] + EPS;
        }

        // beta tail: t -> (row ii, head hh, eighth q of D)
        const int ii = t >> 5;        // 0..15
        const int hh = (t >> 3) & 3;  // 0..3
        const int qq = t & 7;         // 0..7 -> d in [qq*64, qq*64+64)
        const float* hrow = hid + (size_t)(i0 + ii) * D + qq * 64;
        const float* wcb  = Wb + (size_t)(qq * 64) * NH + hh;
        float acc2 = 0.f;
#pragma unroll 4
        for (int d = 0; d < 64; ++d)
            acc2 = fmaf(hrow[d], wcb[(size_t)d * NH], acc2);
        acc2 += __shfl_xor(acc2, 1, 64);
        acc2 += __shfl_xor(acc2, 2, 64);
        acc2 += __shfl_xor(acc2, 4, 64);
        if (qq == 0) {
            const float x = acc2 + bb[hh];
            // stable softplus: max(x,0) + log1p(exp(-|x|))
            bts[ii][hh] = fmaxf(x, 0.f) + log1pf(expf(-fabsf(x)));
        }
    }

    // ---- Phase C: attention, coalesced LDS-staged batches -----------------
    const int q  = t & 3;         // column quarter (16 floats) & owned head
    const int m  = t >> 2;        // memory row 0..127
    const int wv = t >> 6;        // wave 0..7
    float4* hl4 = (float4*)hl;

    float4 nxt[4];
    for (int bl = 0; bl < TILE; ++bl) {
        __syncthreads();   // prev compute done (hl free) / phase-B kl visible
#pragma unroll
        for (int c = 0; c < 4; ++c)
            hl4[swz(t + c * 512)] = cur[c];
        if (bl + 1 < TILE) {
            const float4* nsrc = (const float4*)(mem + (size_t)(i0 + bl + 1) * (M * W));
#pragma unroll
            for (int c = 0; c < 4; ++c) nxt[c] = nsrc[t + c * 512];
        }
        __syncthreads();   // staged tile visible

        // partial dots over cols [q*16, q*16+16)
        float na0 = 0.f, na1 = 0.f, na2 = 0.f, na3 = 0.f, v2 = 0.f;
#pragma unroll
        for (int i = 0; i < 4; ++i) {
            const float4 x = hl4[swz(m * 16 + q * 4 + i)];
            v2 = fmaf(x.x, x.x, fmaf(x.y, x.y, fmaf(x.z, x.z, fmaf(x.w, x.w, v2))));
            const float4 k0 = *(const float4*)&kl[bl][0 * W + q * 16 + i * 4];
            const float4 k1 = *(const float4*)&kl[bl][1 * W + q * 16 + i * 4];
            const float4 k2 = *(const float4*)&kl[bl][2 * W + q * 16 + i * 4];
            const float4 k3 = *(const float4*)&kl[bl][3 * W + q * 16 + i * 4];
            na0 = fmaf(x.x, k0.x, fmaf(x.y, k0.y, fmaf(x.z, k0.z, fmaf(x.w, k0.w, na0))));
            na1 = fmaf(x.x, k1.x, fmaf(x.y, k1.y, fmaf(x.z, k1.z, fmaf(x.w, k1.w, na1))));
            na2 = fmaf(x.x, k2.x, fmaf(x.y, k2.y, fmaf(x.z, k2.z, fmaf(x.w, k2.w, na2))));
            na3 = fmaf(x.x, k3.x, fmaf(x.y, k3.y, fmaf(x.z, k3.z, fmaf(x.w, k3.w, na3))));
        }

        // reduce the 4 quarters of row m (lanes 4m..4m+3)
#pragma unroll
        for (int off = 1; off < 4; off <<= 1) {
            na0 += __shfl_xor(na0, off, 64);
            na1 += __shfl_xor(na1, off, 64);
            na2 += __shfl_xor(na2, off, 64);
            na3 += __shfl_xor(na3, off, 64);
            v2  += __shfl_xor(v2,  off, 64);
        }
        v2 += EPS;

        // lane keeps head q only (cndmask selects, no runtime reg indexing)
        const float na_q = q == 0 ? na0 : q == 1 ? na1 : q == 2 ? na2 : na3;
        const float u2q  = u2s[bl][q];
        const float btq  = bts[bl][q];
        const float lgt  = (na_q / (sqrtf(u2q * v2) + EPS)) * btq;
        const float e    = expf(lgt);   // |lgt| <= beta <~ 3: no overflow

        // sum over the wave's 16 rows (q bits preserved)
        float s_ = e;
#pragma unroll
        for (int off = 4; off < 64; off <<= 1) s_ += __shfl_xor(s_, off, 64);
        if ((t & 63) < 4) red[wv][t & 3] = s_;
        __syncthreads();   // all waves' partial sums visible

        const float tot = red[0][q] + red[1][q] + red[2][q] + red[3][q] +
                          red[4][q] + red[5][q] + red[6][q] + red[7][q];
        out[(size_t)(i0 + bl) * (NH * M) + (size_t)q * M + m] = e / tot;

#pragma unroll
        for (int c = 0; c < 4; ++c) cur[c] = nxt[c];
    }
}

// ---------------------------------------------------------------------------
extern "C" void kernel_launch(void* const* d_in, const int* in_sizes, int n_in,
                              void* d_out, int out_size, void* d_ws, size_t ws_size,
                              hipStream_t stream) {
    const float* hid = (const float*)d_in[0];  // [B, D]
    const float* mem = (const float*)d_in[1];  // [B, M, W]
    const float* Wk  = (const float*)d_in[2];  // [D, HW]
    const float* bk  = (const float*)d_in[3];  // [HW]
    const float* Wb  = (const float*)d_in[4];  // [D, NH]
    const float* bb  = (const float*)d_in[5];  // [NH]
    float* out = (float*)d_out;                // [B, NH, M]

    (void)d_ws; (void)ws_size;  // fully fused: no workspace needed

    fused_dynhead<<<B / TILE, 512, 0, stream>>>(hid, mem, Wk, bk, Wb, bb, out);
}

// Round 5
// 428.547 us; speedup vs baseline: 1.2894x; 1.2894x over previous
//
#include <hip/hip_runtime.h>
#include <math.h>

#define B 8192
#define D 512
#define NH 4
#define M 128
#define W 64
#define HW 256   // NH * W
#define TILE 16  // batch rows per block
#define EPS 1e-6f

// Swizzle in float4 units within a 128x64f batch tile: row = j>>4, col = j&15;
// physical col = col ^ (row&15). Involution: applied on the global SOURCE at
// stage time (LDS dest stays linear, as global_load_lds requires) and on the
// LDS index at read time. Spreads phase C's stride-256B row reads across
// banks (R4 measured 0 conflicts with this exact read pattern).
__device__ __forceinline__ int swz(int j) {
    return (j & ~15) | ((j & 15) ^ ((j >> 4) & 15));
}

// Async global->LDS, 16 B per lane. LDS dest is wave-uniform base + lane*16.
__device__ __forceinline__ void async_copy16(const float* g, float* l) {
    __builtin_amdgcn_global_load_lds(
        (const __attribute__((address_space(1))) void*)g,
        (__attribute__((address_space(3))) void*)l, 16, 0, 0);
}

// ---------------------------------------------------------------------------
// Fully fused kernel: one block = 16 batches, 512 threads.
//
// Phase A: stage hidden tile (16x512, 32 KB) into hl, coalesced float4.
// Phase B: key GEMM (8-row x 1-col/thread, VALU-bound fp32 floor) -> kl;
//          u2 full-wave butterfly -> u2s; beta tail from L2-warm global.
// Phase C: per batch, each wave owns memory rows [16w,16w+16) = a PRIVATE
//          4 KB LDS region staged by its own 4 global_load_lds (pre-swizzled
//          per-lane global src, linear LDS dest). Per-wave s_waitcnt vmcnt(0)
//          replaces buffer barriers entirely; prefetch of batch bl+1 issues
//          right after batch bl's reads are consumed and flies across the
//          softmax tail + combine barrier (raw s_barrier: no vmcnt drain).
//          red[] is parity double-buffered to avoid read/overwrite races.
// R4's regression (WRITE_SIZE 492 MB) was scratch spill of the cur/nxt
// register staging arrays; this version has no register staging at all.
// LDS 49.9 KB -> 2 blocks/CU resident (grid 512), B/C phases overlap.
// ---------------------------------------------------------------------------
__global__ __launch_bounds__(512, 4) void fused_dynhead(const float* __restrict__ hid,
                                                        const float* __restrict__ mem,
                                                        const float* __restrict__ Wk,
                                                        const float* __restrict__ bk,
                                                        const float* __restrict__ Wb,
                                                        const float* __restrict__ bb,
                                                        float* __restrict__ out) {
    const int t  = threadIdx.x;
    const int i0 = blockIdx.x * TILE;

    __shared__ float hl[TILE * D];      // 32 KB: hidden tile, then mem batch tile
    __shared__ float kl[TILE][HW];      // 16 KB key tile
    __shared__ float u2s[TILE][NH];
    __shared__ float bts[TILE][NH];
    __shared__ float red[2][8][NH];     // parity-double-buffered wave partials

    // ---- Phase A: stage hidden --------------------------------------------
    {
        const float4* src = (const float4*)(hid + (size_t)i0 * D);
        float4* dst = (float4*)hl;
#pragma unroll
        for (int c = 0; c < 4; ++c)
            dst[t + c * 512] = src[t + c * 512];
    }
    __syncthreads();

    // ---- Phase B: key GEMM ------------------------------------------------
    float kv[8];
    {
        const int tx = t & 255;       // output column 0..255
        const int ty = t >> 8;        // 0..1 -> rows 8*ty .. 8*ty+7
        const float* hrows = hl + (8 * ty) * D;
        const float* wcol  = Wk + tx;

        float acc[8];
#pragma unroll
        for (int r = 0; r < 8; ++r) acc[r] = 0.f;

#pragma unroll 2
        for (int d = 0; d < D; d += 4) {
            const float w0 = wcol[(size_t)(d + 0) * HW];
            const float w1 = wcol[(size_t)(d + 1) * HW];
            const float w2 = wcol[(size_t)(d + 2) * HW];
            const float w3 = wcol[(size_t)(d + 3) * HW];
#pragma unroll
            for (int r = 0; r < 8; ++r) {
                const float4 x = *(const float4*)&hrows[r * D + d];
                acc[r] = fmaf(x.w, w3, fmaf(x.z, w2, fmaf(x.y, w1, fmaf(x.x, w0, acc[r]))));
            }
        }
        const float bj = bk[tx];
#pragma unroll
        for (int r = 0; r < 8; ++r) kv[r] = tanhf(acc[r] + bj);
    }
    __syncthreads();   // all hl (hidden) reads done -> hl reusable as mem tile

    // ---- batch-0 prefetch into this wave's private region -----------------
    const int wv = t >> 6;        // wave 0..7
    const int l  = t & 63;
    int gsrc4[4];                 // pre-swizzled float4 src index in batch tile
#pragma unroll
    for (int c = 0; c < 4; ++c) gsrc4[c] = swz(wv * 256 + c * 64 + l);
    float4* hl4 = (float4*)hl;

#pragma unroll
    for (int c = 0; c < 4; ++c)
        async_copy16(mem + (size_t)i0 * (M * W) + 4 * gsrc4[c],
                     hl + (wv * 256 + c * 64) * 4);

    // ---- Phase B tail: kl/u2 writes + beta (overlaps batch-0 loads) -------
    {
        const int tx = t & 255;
        const int ty = t >> 8;
#pragma unroll
        for (int r = 0; r < 8; ++r) kl[8 * ty + r][tx] = kv[r];

        float s[8];
#pragma unroll
        for (int r = 0; r < 8; ++r) s[r] = kv[r] * kv[r];
#pragma unroll
        for (int off = 1; off < 64; off <<= 1) {
#pragma unroll
            for (int r = 0; r < 8; ++r) s[r] += __shfl_xor(s[r], off, 64);
        }
        if ((t & 63) == 0) {
            const int h = (t >> 6) & 3;   // wave within ty-half = head
#pragma unroll
            for (int r = 0; r < 8; ++r)
                u2s[8 * ty + r][h] = s[r] + EPS;
        }

        // beta tail: t -> (row ii, head hh, eighth qq of D)
        const int ii = t >> 5;
        const int hh = (t >> 3) & 3;
        const int qq = t & 7;
        const float* hrow = hid + (size_t)(i0 + ii) * D + qq * 64;
        const float* wcb  = Wb + (size_t)(qq * 64) * NH + hh;
        float acc2 = 0.f;
#pragma unroll 4
        for (int d = 0; d < 64; ++d)
            acc2 = fmaf(hrow[d], wcb[(size_t)d * NH], acc2);
        acc2 += __shfl_xor(acc2, 1, 64);
        acc2 += __shfl_xor(acc2, 2, 64);
        acc2 += __shfl_xor(acc2, 4, 64);
        if (qq == 0) {
            const float x = acc2 + bb[hh];
            bts[ii][hh] = fmaxf(x, 0.f) + log1pf(expf(-fabsf(x)));
        }
    }
    // raw barrier: publishes kl/u2s/bts (lgkm) WITHOUT draining vmcnt,
    // so the batch-0 prefetch stays in flight.
    asm volatile("s_waitcnt lgkmcnt(0)" ::: "memory");
    __builtin_amdgcn_s_barrier();
    __builtin_amdgcn_sched_barrier(0);

    // ---- Phase C: attention -----------------------------------------------
    const int q = t & 3;          // owned head & column quarter
    const int m = t >> 2;         // memory row 0..127 (wave wv owns 16 rows)

    for (int bl = 0; bl < TILE; ++bl) {
        // own region's loads (issued last iteration / prologue) complete
        asm volatile("s_waitcnt vmcnt(0)" ::: "memory");
        __builtin_amdgcn_sched_barrier(0);

        // partial dots over cols [q*16, q*16+16)
        float na0 = 0.f, na1 = 0.f, na2 = 0.f, na3 = 0.f, v2 = 0.f;
#pragma unroll
        for (int i = 0; i < 4; ++i) {
            const float4 x = hl4[swz(m * 16 + q * 4 + i)];
            v2 = fmaf(x.x, x.x, fmaf(x.y, x.y, fmaf(x.z, x.z, fmaf(x.w, x.w, v2))));
            const float4 k0 = *(const float4*)&kl[bl][0 * W + q * 16 + i * 4];
            const float4 k1 = *(const float4*)&kl[bl][1 * W + q * 16 + i * 4];
            const float4 k2 = *(const float4*)&kl[bl][2 * W + q * 16 + i * 4];
            const float4 k3 = *(const float4*)&kl[bl][3 * W + q * 16 + i * 4];
            na0 = fmaf(x.x, k0.x, fmaf(x.y, k0.y, fmaf(x.z, k0.z, fmaf(x.w, k0.w, na0))));
            na1 = fmaf(x.x, k1.x, fmaf(x.y, k1.y, fmaf(x.z, k1.z, fmaf(x.w, k1.w, na1))));
            na2 = fmaf(x.x, k2.x, fmaf(x.y, k2.y, fmaf(x.z, k2.z, fmaf(x.w, k2.w, na2))));
            na3 = fmaf(x.x, k3.x, fmaf(x.y, k3.y, fmaf(x.z, k3.z, fmaf(x.w, k3.w, na3))));
        }

        // reduce the 4 quarters of row m (lanes 4m..4m+3)
#pragma unroll
        for (int off = 1; off < 4; off <<= 1) {
            na0 += __shfl_xor(na0, off, 64);
            na1 += __shfl_xor(na1, off, 64);
            na2 += __shfl_xor(na2, off, 64);
            na3 += __shfl_xor(na3, off, 64);
            v2  += __shfl_xor(v2,  off, 64);
        }
        v2 += EPS;

        // all reads of this wave's region are consumed -> refill with bl+1
        if (bl + 1 < TILE) {
            const float* nb = mem + (size_t)(i0 + bl + 1) * (M * W);
#pragma unroll
            for (int c = 0; c < 4; ++c)
                async_copy16(nb + 4 * gsrc4[c], hl + (wv * 256 + c * 64) * 4);
        }

        // lane keeps head q only
        const float na_q = q == 0 ? na0 : q == 1 ? na1 : q == 2 ? na2 : na3;
        const float u2q  = u2s[bl][q];
        const float btq  = bts[bl][q];
        const float lgt  = (na_q / (sqrtf(u2q * v2) + EPS)) * btq;
        const float e    = expf(lgt);   // |lgt| <= beta <~ 3: no overflow

        // sum over the wave's 16 rows (q bits preserved)
        float s_ = e;
#pragma unroll
        for (int off = 4; off < 64; off <<= 1) s_ += __shfl_xor(s_, off, 64);
        if (l < 4) red[bl & 1][wv][l] = s_;

        // raw barrier: publishes red (lgkm) without draining the prefetch
        asm volatile("s_waitcnt lgkmcnt(0)" ::: "memory");
        __builtin_amdgcn_s_barrier();
        __builtin_amdgcn_sched_barrier(0);

        const float tot = red[bl & 1][0][q] + red[bl & 1][1][q] +
                          red[bl & 1][2][q] + red[bl & 1][3][q] +
                          red[bl & 1][4][q] + red[bl & 1][5][q] +
                          red[bl & 1][6][q] + red[bl & 1][7][q];
        out[(size_t)(i0 + bl) * (NH * M) + (size_t)q * M + m] = e / tot;
    }
}

// ---------------------------------------------------------------------------
extern "C" void kernel_launch(void* const* d_in, const int* in_sizes, int n_in,
                              void* d_out, int out_size, void* d_ws, size_t ws_size,
                              hipStream_t stream) {
    const float* hid = (const float*)d_in[0];  // [B, D]
    const float* mem = (const float*)d_in[1];  // [B, M, W]
    const float* Wk  = (const float*)d_in[2];  // [D, HW]
    const float* bk  = (const float*)d_in[3];  // [HW]
    const float* Wb  = (const float*)d_in[4];  // [D, NH]
    const float* bb  = (const float*)d_in[5];  // [NH]
    float* out = (float*)d_out;                // [B, NH, M]

    (void)d_ws; (void)ws_size;  // fully fused: no workspace needed

    fused_dynhead<<<B / TILE, 512, 0, stream>>>(hid, mem, Wk, bk, Wb, bb, out);
}